// Round 1
// 799.420 us; speedup vs baseline: 1.4484x; 1.4484x over previous
//
#include <hip/hip_runtime.h>
#include <hip/hip_bf16.h>

typedef unsigned short u16;
typedef unsigned int u32;
typedef __bf16 bf16x8 __attribute__((ext_vector_type(8)));
typedef float f32x4 __attribute__((ext_vector_type(4)));

#define SDIM 512
#define BDIM 2
#define DDIM 1024
#define VDIM 32000
#define FCTX 16
#define NROWS (BDIM * SDIM)          // 1024 GEMM M
#define YSTR (SDIM + FCTX - 1)       // 527
#define CONV_CHUNK 64                // s-positions per conv block (multiple of 16)

__device__ __forceinline__ u16 f2bf(float f) {
    u32 u = __float_as_uint(f);
    u += 0x7fffu + ((u >> 16) & 1u);   // RNE
    return (u16)(u >> 16);
}

__device__ __forceinline__ void gload_lds16(const void* g, void* l) {
    __builtin_amdgcn_global_load_lds((const __attribute__((address_space(1))) void*)g,
                                     (__attribute__((address_space(3))) void*)l, 16, 0, 0);
}

// ---------------- prep: layernorm + bf16 cast of A panels ----------------
__global__ __launch_bounds__(256) void prep_a_kernel(
    const float* __restrict__ emb, const float* __restrict__ lnw,
    u16* __restrict__ Alm, u16* __restrict__ Actx)
{
    int row = blockIdx.x;
    int t = threadIdx.x;
    const float4* x4 = (const float4*)(emb + (size_t)row * DDIM);
    float4 v = x4[t];
    float s1 = v.x + v.y + v.z + v.w;
    float s2 = v.x*v.x + v.y*v.y + v.z*v.z + v.w*v.w;
#pragma unroll
    for (int off = 32; off; off >>= 1) {
        s1 += __shfl_down(s1, off, 64);
        s2 += __shfl_down(s2, off, 64);
    }
    __shared__ float r1[4], r2[4];
    int lane = t & 63, wave = t >> 6;
    if (lane == 0) { r1[wave] = s1; r2[wave] = s2; }
    __syncthreads();
    s1 = r1[0] + r1[1] + r1[2] + r1[3];
    s2 = r2[0] + r2[1] + r2[2] + r2[3];
    float mean = s1 * (1.f / DDIM);
    float var = s2 * (1.f / DDIM) - mean * mean;
    float rstd = rsqrtf(var + 1e-5f);
    float4 w = ((const float4*)lnw)[t];
    ushort4 a, b;
    a.x = f2bf(v.x); a.y = f2bf(v.y); a.z = f2bf(v.z); a.w = f2bf(v.w);
    b.x = f2bf((v.x - mean) * rstd * w.x);
    b.y = f2bf((v.y - mean) * rstd * w.y);
    b.z = f2bf((v.z - mean) * rstd * w.z);
    b.w = f2bf((v.w - mean) * rstd * w.w);
    ((ushort4*)(Alm + (size_t)row * DDIM))[t] = a;
    ((ushort4*)(Actx + (size_t)row * DDIM))[t] = b;
}

// ---------------- cast W fp32 -> bf16 ----------------
__global__ __launch_bounds__(256) void cast_kernel(
    const float4* __restrict__ src, ushort4* __restrict__ dst)
{
    int i = blockIdx.x * 256 + threadIdx.x;   // exactly V*D/4 threads
    float4 f = src[i];
    ushort4 o;
    o.x = f2bf(f.x); o.y = f2bf(f.y); o.z = f2bf(f.z); o.w = f2bf(f.w);
    dst[i] = o;
}

// ---------------- dual GEMM: C[M,N] = A[M,K] * W[N,K]^T (bf16 -> f32) ----------------
// m97 structure: 128x128 tile, BK=32, 4 waves, 4x4 16x16x32 MFMA per wave.
__global__ __launch_bounds__(256) void gemm_kernel(
    const u16* __restrict__ A0, const u16* __restrict__ B0, float* __restrict__ C0,
    const u16* __restrict__ A1, const u16* __restrict__ B1, float* __restrict__ C1)
{
    constexpr int K = DDIM, N = VDIM;
    const u16* A; const u16* Bw; float* C;
    if (blockIdx.z == 0) { A = A0; Bw = B0; C = C0; }
    else                 { A = A1; Bw = B1; C = C1; }

    __shared__ __align__(16) u16 sA[128 * 32];
    __shared__ __align__(16) u16 sB[128 * 32];

    int t = threadIdx.x;
    int lane = t & 63, wave = t >> 6;
    int bm = blockIdx.x, bn = blockIdx.y;

    // staging: thread t loads 16B: row = t/4 (+64), kchunk = t%4; LDS = contiguous t*16B
    const u16* gA = A + (size_t)(bm * 128 + (t >> 2)) * K + (t & 3) * 8;
    const u16* gB = Bw + (size_t)(bn * 128 + (t >> 2)) * K + (t & 3) * 8;
    u16* lA = sA + t * 8;
    u16* lB = sB + t * 8;

    f32x4 acc[4][4] = {};

    int wrow = (wave >> 1) * 64;
    int wcol = (wave & 1) * 64;
    const u16* fA = sA + (wrow + (lane & 15)) * 32 + (lane >> 4) * 8;
    const u16* fB = sB + (wcol + (lane & 15)) * 32 + (lane >> 4) * 8;

    for (int kt = 0; kt < K; kt += 32) {
        gload_lds16(gA,           lA);
        gload_lds16(gA + 64 * K,  lA + 2048);
        gload_lds16(gB,           lB);
        gload_lds16(gB + 64 * K,  lB + 2048);
        gA += 32; gB += 32;
        __syncthreads();   // drains vmcnt before barrier -> staging visible
        bf16x8 af[4], bfr[4];
#pragma unroll
        for (int i = 0; i < 4; ++i) af[i] = *(const bf16x8*)(fA + i * 16 * 32);
#pragma unroll
        for (int j = 0; j < 4; ++j) bfr[j] = *(const bf16x8*)(fB + j * 16 * 32);
#pragma unroll
        for (int i = 0; i < 4; ++i)
#pragma unroll
            for (int j = 0; j < 4; ++j)
                acc[i][j] = __builtin_amdgcn_mfma_f32_16x16x32_bf16(af[i], bfr[j], acc[i][j], 0, 0, 0);
        __syncthreads();   // protect LDS from next iter's staging
    }

    // epilogue: D row = quad*4+r, col = lane&15
    int q = lane >> 4, lr = lane & 15;
    int row0 = bm * 128 + wrow + q * 4;
    int col0 = bn * 128 + wcol + lr;
#pragma unroll
    for (int i = 0; i < 4; ++i)
#pragma unroll
        for (int j = 0; j < 4; ++j) {
            float* cp = C + (size_t)(row0 + i * 16) * N + col0 + j * 16;
#pragma unroll
            for (int r = 0; r < 4; ++r) cp[(size_t)r * N] = acc[i][j][r];
        }
}

// ---------------- conv (exp-decay causal window) + softplus-sum ----------------
// s-dimension tiled across blocks (CONV_CHUNK positions each + 15-halo) so the
// grid is 2000 blocks -> full occupancy instead of 250 blocks (11%).
__global__ __launch_bounds__(256) void conv_kernel(
    const float* __restrict__ c, float* __restrict__ logits, float* __restrict__ acc)
{
    int v = blockIdx.x * 256 + threadIdx.x;   // 0..31999
    int s0 = blockIdx.y * CONV_CHUNK;         // chunk start (multiple of 16)
    int b = blockIdx.z;

    float coef[FCTX];
    float Z = 0.f;
#pragma unroll
    for (int i = 0; i < FCTX; ++i) { coef[i] = expf(-0.5f * i); Z += coef[i]; }
    float invZ = 1.f / Z;
#pragma unroll
    for (int i = 0; i < FCTX; ++i) coef[i] *= invZ;

    float ring[FCTX];
#pragma unroll
    for (int i = 0; i < FCTX; ++i) ring[i] = 0.f;

    size_t base = ((size_t)b * SDIM) * VDIM + v;

    // halo: load c[s0-15 .. s0-1] into ring slots (s & 15) = 1..15.
    // s0 is a multiple of 16, so slot index == loop index (compile-time, no scratch).
    if (s0 > 0) {
#pragma unroll
        for (int i = 1; i < FCTX; ++i) {
            int s = s0 - FCTX + i;            // s mod 16 == i
            ring[i] = c[base + (size_t)s * VDIM];
        }
    }

    float sp = 0.f;
    for (int t16 = 0; t16 < CONV_CHUNK; t16 += FCTX) {
#pragma unroll
        for (int u = 0; u < FCTX; ++u) {
            size_t off = base + (size_t)(s0 + t16 + u) * VDIM;
            float cv = c[off];
            ring[u] = cv;
            float ctx = 0.f;
#pragma unroll
            for (int i = 0; i < FCTX; ++i) ctx += coef[i] * ring[(u - i) & (FCTX - 1)];
            logits[off] += ctx;
            sp += fmaxf(cv, 0.f) + log1pf(expf(-fabsf(cv)));   // softplus(cv), owned s only
        }
    }
    // block reduce sp -> one atomic
#pragma unroll
    for (int off = 32; off; off >>= 1) sp += __shfl_down(sp, off, 64);
    __shared__ float rs[4];
    int lane = threadIdx.x & 63, wave = threadIdx.x >> 6;
    if (lane == 0) rs[wave] = sp;
    __syncthreads();
    if (threadIdx.x == 0) atomicAdd(acc + 1, rs[0] + rs[1] + rs[2] + rs[3]);
}

// ---------------- BCE correction terms (t=1 entries + duplicate weights) ----------------
__device__ __forceinline__ float softplus(float x) {
    return fmaxf(x, 0.f) + log1pf(expf(-fabsf(x)));
}

__global__ __launch_bounds__(256) void corr_kernel(
    const float* __restrict__ c, const int* __restrict__ y, float* __restrict__ acc)
{
    int sid = blockIdx.x * 256 + threadIdx.x;
    float corr = 0.f;
    if (sid < SDIM) {
        int tok[2 * FCTX];
        for (int i = 0; i < FCTX; ++i) {
            tok[i] = y[sid + i];
            tok[FCTX + i] = y[YSTR + sid + i];
        }
        for (int k = 0; k < 2 * FCTX; ++k) {
            int v = tok[k];
            bool seen = false;
            for (int j = 0; j < k; ++j) seen |= (tok[j] == v);
            if (seen) continue;
            int c0 = 0, c1 = 0;
            for (int i = 0; i < FCTX; ++i) {
                c0 += (tok[i] == v);
                c1 += (tok[FCTX + i] == v);
            }
            float w = ((c0 > 1) || (c1 > 1)) ? 1.5f : 1.0f;
            float cv0 = c[(size_t)sid * VDIM + v];
            float cv1 = c[(size_t)(SDIM + sid) * VDIM + v];
            if (w > 1.f) corr += 0.5f * (softplus(cv0) + softplus(cv1));
            if (c0 > 0) corr -= w * cv0;
            if (c1 > 0) corr -= w * cv1;
        }
    }
    atomicAdd(acc + 1, corr);
}

// ---------------- NLL over final logits (online softmax) ----------------
__global__ __launch_bounds__(256) void loss_kernel(
    const float* __restrict__ logits, const int* __restrict__ y, float* __restrict__ acc)
{
    int row = blockIdx.x;  // 0..1023
    int t = threadIdx.x;
    const float* lp = logits + (size_t)row * VDIM;
    float m = -3.4e38f, sum = 0.f;
    for (int i = t; i < VDIM; i += 256) {
        float x = lp[i];
        float nm = fmaxf(m, x);
        sum = sum * expf(m - nm) + expf(x - nm);
        m = nm;
    }
#pragma unroll
    for (int off = 32; off; off >>= 1) {
        float om = __shfl_down(m, off, 64);
        float os = __shfl_down(sum, off, 64);
        float nm = fmaxf(m, om);
        sum = sum * expf(m - nm) + os * expf(om - nm);
        m = nm;
    }
    __shared__ float sm[4], ss[4];
    int lane = t & 63, wave = t >> 6;
    if (lane == 0) { sm[wave] = m; ss[wave] = sum; }
    __syncthreads();
    if (t == 0) {
        float M = sm[0], S = ss[0];
        for (int wv = 1; wv < 4; ++wv) {
            float nm = fmaxf(M, sm[wv]);
            S = S * expf(M - nm) + ss[wv] * expf(sm[wv] - nm);
            M = nm;
        }
        int b = row >> 9, s = row & 511;
        int tgt = y[b * YSTR + s];
        float xt = lp[tgt];
        atomicAdd(acc, -(xt - M - logf(S)));
    }
}

__global__ void finalize_kernel(const float* __restrict__ acc, float* __restrict__ out)
{
    out[(size_t)NROWS * VDIM]     = acc[0] * (1.f / (float)NROWS);
    out[(size_t)NROWS * VDIM + 1] = acc[1] * (1.f / ((float)NROWS * (float)VDIM));
}

extern "C" void kernel_launch(void* const* d_in, const int* in_sizes, int n_in,
                              void* d_out, int out_size, void* d_ws, size_t ws_size,
                              hipStream_t stream)
{
    const float* emb  = (const float*)d_in[0];
    const float* Wlm  = (const float*)d_in[1];
    const float* Wctx = (const float*)d_in[2];
    const float* lnw  = (const float*)d_in[3];
    const int*   y    = (const int*)d_in[4];
    float* out = (float*)d_out;

    // ws layout (all 16B aligned)
    char* ws = (char*)d_ws;
    const size_t A_BYTES = (size_t)NROWS * DDIM * 2;       // 2 MB each
    const size_t W_BYTES = (size_t)VDIM * DDIM * 2;        // 65.536 MB each
    const size_t C_BYTES = (size_t)NROWS * VDIM * 4;       // 131.072 MB
    u16*   Alm   = (u16*)ws;
    u16*   Actx  = (u16*)(ws + A_BYTES);
    u16*   WlmB  = (u16*)(ws + 2 * A_BYTES);
    u16*   WctxB = (u16*)(ws + 2 * A_BYTES + W_BYTES);
    float* c     = (float*)(ws + 2 * A_BYTES + 2 * W_BYTES);
    float* acc   = (float*)(ws + 2 * A_BYTES + 2 * W_BYTES + C_BYTES);

    hipMemsetAsync(acc, 0, 2 * sizeof(float), stream);
    prep_a_kernel<<<NROWS, 256, 0, stream>>>(emb, lnw, Alm, Actx);
    cast_kernel<<<(VDIM * DDIM / 4) / 256, 256, 0, stream>>>((const float4*)Wlm,  (ushort4*)WlmB);
    cast_kernel<<<(VDIM * DDIM / 4) / 256, 256, 0, stream>>>((const float4*)Wctx, (ushort4*)WctxB);
    gemm_kernel<<<dim3(NROWS / 128, VDIM / 128, 2), 256, 0, stream>>>(Alm, WlmB, out, Actx, WctxB, c);
    conv_kernel<<<dim3(VDIM / 256, SDIM / CONV_CHUNK, BDIM), 256, 0, stream>>>(c, out, acc);
    corr_kernel<<<2, 256, 0, stream>>>(c, y, acc);
    loss_kernel<<<NROWS, 256, 0, stream>>>(out, y, acc);
    finalize_kernel<<<1, 1, 0, stream>>>(acc, out);
}

// Round 2
// 688.035 us; speedup vs baseline: 1.6829x; 1.1619x over previous
//
#include <hip/hip_runtime.h>
#include <hip/hip_bf16.h>

typedef unsigned short u16;
typedef unsigned int u32;
typedef __bf16 bf16x8 __attribute__((ext_vector_type(8)));
typedef float f32x4 __attribute__((ext_vector_type(4)));

#define SDIM 512
#define BDIM 2
#define DDIM 1024
#define VDIM 32000
#define FCTX 16
#define NROWS (BDIM * SDIM)          // 1024 GEMM M
#define YSTR (SDIM + FCTX - 1)       // 527
#define CONV_CHUNK 64                // s-positions per conv block (multiple of 16)

__device__ __forceinline__ u16 f2bf(float f) {
    u32 u = __float_as_uint(f);
    u += 0x7fffu + ((u >> 16) & 1u);   // RNE
    return (u16)(u >> 16);
}

__device__ __forceinline__ void gload_lds16(const void* g, void* l) {
    __builtin_amdgcn_global_load_lds((const __attribute__((address_space(1))) void*)g,
                                     (__attribute__((address_space(3))) void*)l, 16, 0, 0);
}

// ---------------- prep: layernorm + bf16 cast of A panels ----------------
__global__ __launch_bounds__(256) void prep_a_kernel(
    const float* __restrict__ emb, const float* __restrict__ lnw,
    u16* __restrict__ Alm, u16* __restrict__ Actx)
{
    int row = blockIdx.x;
    int t = threadIdx.x;
    const float4* x4 = (const float4*)(emb + (size_t)row * DDIM);
    float4 v = x4[t];
    float s1 = v.x + v.y + v.z + v.w;
    float s2 = v.x*v.x + v.y*v.y + v.z*v.z + v.w*v.w;
#pragma unroll
    for (int off = 32; off; off >>= 1) {
        s1 += __shfl_down(s1, off, 64);
        s2 += __shfl_down(s2, off, 64);
    }
    __shared__ float r1[4], r2[4];
    int lane = t & 63, wave = t >> 6;
    if (lane == 0) { r1[wave] = s1; r2[wave] = s2; }
    __syncthreads();
    s1 = r1[0] + r1[1] + r1[2] + r1[3];
    s2 = r2[0] + r2[1] + r2[2] + r2[3];
    float mean = s1 * (1.f / DDIM);
    float var = s2 * (1.f / DDIM) - mean * mean;
    float rstd = rsqrtf(var + 1e-5f);
    float4 w = ((const float4*)lnw)[t];
    ushort4 a, b;
    a.x = f2bf(v.x); a.y = f2bf(v.y); a.z = f2bf(v.z); a.w = f2bf(v.w);
    b.x = f2bf((v.x - mean) * rstd * w.x);
    b.y = f2bf((v.y - mean) * rstd * w.y);
    b.z = f2bf((v.z - mean) * rstd * w.z);
    b.w = f2bf((v.w - mean) * rstd * w.w);
    ((ushort4*)(Alm + (size_t)row * DDIM))[t] = a;
    ((ushort4*)(Actx + (size_t)row * DDIM))[t] = b;
}

// ---------------- cast W fp32 -> bf16 ----------------
__global__ __launch_bounds__(256) void cast_kernel(
    const float4* __restrict__ src, ushort4* __restrict__ dst)
{
    int i = blockIdx.x * 256 + threadIdx.x;   // exactly V*D/4 threads
    float4 f = src[i];
    ushort4 o;
    o.x = f2bf(f.x); o.y = f2bf(f.y); o.z = f2bf(f.z); o.w = f2bf(f.w);
    dst[i] = o;
}

// ---------------- dual GEMM: C[M,N] = A[M,K] * W[N,K]^T (bf16 -> f32) ----------------
// 256x256 tile, BK=64, 8 waves (2Mx4N), 8-phase schedule w/ counted vmcnt (T2+T3+T4+T5).
// LDS: 2 bufs x (A: 2x 128x64 halves + B: 2x 128x64 halves) x 16KB = 128 KiB.
// Swizzle: logical (row r, col-byte cb) stored at physical cb ^ ((r&7)<<4); inverse applied
// to the global SOURCE address for global_load_lds (linear LDS dest), XOR applied on ds_read.
// Hazard schedule (iteration m computes K-tiles 2m (buf0), 2m+1 (buf1)); stages per phase:
//  P1: buf1.a0<-K(2m+1)  P2: buf1.a1<-K(2m+1)   [read P5-P8 this iter; landed via vmcnt(4)@P4]
//  P3: buf0.b0<-K(2m+2)  P4: buf0.b1<-K(2m+2)+vmcnt(4)
//  P5: buf0.a0<-K(2m+2)  P6: buf0.a1<-K(2m+2)   [read P1-P4 next iter; landed via vmcnt(4)@P8]
//  P7: buf1.b0<-K(2m+3)  P8: buf1.b1<-K(2m+3)+vmcnt(4)
// Every stage target's previous content is fully ds_read (+lgkmcnt0+barrier) before issue.

__device__ __forceinline__ void stage_half(const u16* __restrict__ mat, int grow0, int gcol0,
                                           char* lds_half, int t)
{
    int r0 = t >> 3;
    int swz = ((t & 7) ^ (r0 & 7)) * 8;     // inverse (= same) XOR on source col, elems
    const u16* g0 = mat + (size_t)(grow0 + r0) * DDIM + gcol0 + swz;
    gload_lds16(g0, lds_half + t * 16);
    gload_lds16(g0 + (size_t)64 * DDIM, lds_half + 8192 + t * 16);
}

#define MFMA16(a, b, c) __builtin_amdgcn_mfma_f32_16x16x32_bf16(a, b, c, 0, 0, 0)
#define VM4 asm volatile("s_waitcnt vmcnt(4)" ::: "memory")
#define VM0 asm volatile("s_waitcnt vmcnt(0)" ::: "memory")
#define NOP ((void)0)

#define PHASE(BB, Q, STG, VM) do {                                              \
    bf16x8 a00, a01, a10, a11;                                                  \
    if ((Q) == 0) {                                                             \
        _Pragma("unroll")                                                       \
        for (int j = 0; j < 4; ++j) {                                           \
            bfr[2*j]   = *(const bf16x8*)(Bln + (BB)*65536 + j*2048 + axor0);   \
            bfr[2*j+1] = *(const bf16x8*)(Bln + (BB)*65536 + j*2048 + axor1);   \
        }                                                                       \
    }                                                                           \
    { const char* Ab = Aln + (BB)*65536 + (2*(Q))*2048;                         \
      a00 = *(const bf16x8*)(Ab + axor0);                                       \
      a01 = *(const bf16x8*)(Ab + axor1);                                       \
      a10 = *(const bf16x8*)(Ab + 2048 + axor0);                                \
      a11 = *(const bf16x8*)(Ab + 2048 + axor1); }                              \
    STG; VM;                                                                    \
    __builtin_amdgcn_s_barrier();                                               \
    asm volatile("s_waitcnt lgkmcnt(0)" ::: "memory");                          \
    __builtin_amdgcn_sched_barrier(0);                                          \
    __builtin_amdgcn_s_setprio(1);                                              \
    _Pragma("unroll")                                                           \
    for (int j = 0; j < 4; ++j) {                                               \
        acc[2*(Q)][j]   = MFMA16(a00, bfr[2*j],   acc[2*(Q)][j]);               \
        acc[2*(Q)][j]   = MFMA16(a01, bfr[2*j+1], acc[2*(Q)][j]);               \
        acc[2*(Q)+1][j] = MFMA16(a10, bfr[2*j],   acc[2*(Q)+1][j]);             \
        acc[2*(Q)+1][j] = MFMA16(a11, bfr[2*j+1], acc[2*(Q)+1][j]);             \
    }                                                                           \
    __builtin_amdgcn_s_setprio(0);                                              \
    __builtin_amdgcn_s_barrier();                                               \
} while (0)

#define STAGE_A(BB, H, KT) stage_half(Amat, bm256 + (H)*128, (KT)*64, ldsb + (BB)*65536 + (H)*16384, t)
#define STAGE_B(BB, H, KT) stage_half(Bmat, bn256 + (H)*128, (KT)*64, ldsb + (BB)*65536 + 32768 + (H)*16384, t)

__global__ __launch_bounds__(512, 2) void gemm_kernel(
    const u16* __restrict__ A0, const u16* __restrict__ B0, float* __restrict__ C0,
    const u16* __restrict__ A1, const u16* __restrict__ B1, float* __restrict__ C1)
{
    constexpr int N = VDIM;
    __shared__ __align__(16) char lds_s[131072];
    char* ldsb = lds_s;

    // XCD-aware bijective swizzle: 1000 wgs, 1000 % 8 == 0. Each XCD gets a contiguous
    // chunk of wg-space so the 4 bm-tiles sharing a W-panel co-reside on one XCD L2.
    int bid = blockIdx.x;
    int wg = (bid & 7) * 125 + (bid >> 3);
    int z = (wg >= 500) ? 1 : 0;
    int rem = wg - z * 500;
    int bn = rem >> 2, bm = rem & 3;

    const u16* Amat; const u16* Bmat; float* C;
    if (z == 0) { Amat = A0; Bmat = B0; C = C0; }
    else        { Amat = A1; Bmat = B1; C = C1; }

    int t = threadIdx.x;
    int lane = t & 63, wave = t >> 6;
    int wr = wave >> 2, wc = wave & 3;       // 2 x 4 wave grid; per-wave out = 128x64
    int l15 = lane & 15, lg = lane >> 4, l7 = lane & 7;
    int bm256 = bm * 256, bn256 = bn * 256;

    int axor0 = (lg * 16) ^ (l7 << 4);
    int axor1 = (64 + lg * 16) ^ (l7 << 4);
    const char* Aln = ldsb + wr * 16384 + l15 * 128;                       // + BB*65536 + i*2048
    const char* Bln = ldsb + 32768 + (wc >> 1) * 16384 + ((wc & 1) * 64 + l15) * 128;

    f32x4 acc[8][4] = {};
    bf16x8 bfr[8];

    // prologue: buf0 <- K0 (all 4 halves), buf1 <- K1 (B halves only)
    STAGE_A(0, 0, 0); STAGE_A(0, 1, 0); STAGE_B(0, 0, 0); STAGE_B(0, 1, 0);
    STAGE_B(1, 0, 1); STAGE_B(1, 1, 1);
    VM4;                                     // first 8 loads (buf0) landed; buf1.b in flight
    __builtin_amdgcn_s_barrier();

    for (int m = 0; m < 7; ++m) {
        int k1 = 2 * m + 1, k2 = 2 * m + 2, k3 = 2 * m + 3;
        PHASE(0, 0, STAGE_A(1, 0, k1), NOP);
        PHASE(0, 1, STAGE_A(1, 1, k1), NOP);
        PHASE(0, 2, STAGE_B(0, 0, k2), NOP);
        PHASE(0, 3, STAGE_B(0, 1, k2), VM4);
        PHASE(1, 0, STAGE_A(0, 0, k2), NOP);
        PHASE(1, 1, STAGE_A(0, 1, k2), NOP);
        PHASE(1, 2, STAGE_B(1, 0, k3), NOP);
        PHASE(1, 3, STAGE_B(1, 1, k3), VM4);
    }
    // peeled m = 7: only K15's A halves remain to stage; drain fully before P5-P8 reads.
    PHASE(0, 0, STAGE_A(1, 0, 15), NOP);
    PHASE(0, 1, STAGE_A(1, 1, 15), NOP);
    PHASE(0, 2, NOP, NOP);
    PHASE(0, 3, NOP, VM0);
    PHASE(1, 0, NOP, NOP);
    PHASE(1, 1, NOP, NOP);
    PHASE(1, 2, NOP, NOP);
    PHASE(1, 3, NOP, NOP);

    // epilogue: C/D map col = lane&15, row = (lane>>4)*4 + reg
    int row0 = bm256 + wr * 128 + lg * 4;
    int col0 = bn256 + wc * 64 + l15;
#pragma unroll
    for (int i = 0; i < 8; ++i)
#pragma unroll
        for (int j = 0; j < 4; ++j) {
            float* cp = C + (size_t)(row0 + i * 16) * N + col0 + j * 16;
#pragma unroll
            for (int r = 0; r < 4; ++r) cp[(size_t)r * N] = acc[i][j][r];
        }
}

// ---------------- conv (exp-decay causal window) + softplus-sum ----------------
__global__ __launch_bounds__(256) void conv_kernel(
    const float* __restrict__ c, float* __restrict__ logits, float* __restrict__ acc)
{
    int v = blockIdx.x * 256 + threadIdx.x;   // 0..31999
    int s0 = blockIdx.y * CONV_CHUNK;         // chunk start (multiple of 16)
    int b = blockIdx.z;

    float coef[FCTX];
    float Z = 0.f;
#pragma unroll
    for (int i = 0; i < FCTX; ++i) { coef[i] = expf(-0.5f * i); Z += coef[i]; }
    float invZ = 1.f / Z;
#pragma unroll
    for (int i = 0; i < FCTX; ++i) coef[i] *= invZ;

    float ring[FCTX];
#pragma unroll
    for (int i = 0; i < FCTX; ++i) ring[i] = 0.f;

    size_t base = ((size_t)b * SDIM) * VDIM + v;

    if (s0 > 0) {
#pragma unroll
        for (int i = 1; i < FCTX; ++i) {
            int s = s0 - FCTX + i;            // s mod 16 == i
            ring[i] = c[base + (size_t)s * VDIM];
        }
    }

    float sp = 0.f;
    for (int t16 = 0; t16 < CONV_CHUNK; t16 += FCTX) {
#pragma unroll
        for (int u = 0; u < FCTX; ++u) {
            size_t off = base + (size_t)(s0 + t16 + u) * VDIM;
            float cv = c[off];
            ring[u] = cv;
            float ctx = 0.f;
#pragma unroll
            for (int i = 0; i < FCTX; ++i) ctx += coef[i] * ring[(u - i) & (FCTX - 1)];
            logits[off] += ctx;
            sp += fmaxf(cv, 0.f) + log1pf(expf(-fabsf(cv)));   // softplus(cv), owned s only
        }
    }
#pragma unroll
    for (int off = 32; off; off >>= 1) sp += __shfl_down(sp, off, 64);
    __shared__ float rs[4];
    int lane = threadIdx.x & 63, wave = threadIdx.x >> 6;
    if (lane == 0) rs[wave] = sp;
    __syncthreads();
    if (threadIdx.x == 0) atomicAdd(acc + 1, rs[0] + rs[1] + rs[2] + rs[3]);
}

// ---------------- BCE correction terms (t=1 entries + duplicate weights) ----------------
__device__ __forceinline__ float softplus(float x) {
    return fmaxf(x, 0.f) + log1pf(expf(-fabsf(x)));
}

__global__ __launch_bounds__(256) void corr_kernel(
    const float* __restrict__ c, const int* __restrict__ y, float* __restrict__ acc)
{
    int sid = blockIdx.x * 256 + threadIdx.x;
    float corr = 0.f;
    if (sid < SDIM) {
        int tok[2 * FCTX];
        for (int i = 0; i < FCTX; ++i) {
            tok[i] = y[sid + i];
            tok[FCTX + i] = y[YSTR + sid + i];
        }
        for (int k = 0; k < 2 * FCTX; ++k) {
            int v = tok[k];
            bool seen = false;
            for (int j = 0; j < k; ++j) seen |= (tok[j] == v);
            if (seen) continue;
            int c0 = 0, c1 = 0;
            for (int i = 0; i < FCTX; ++i) {
                c0 += (tok[i] == v);
                c1 += (tok[FCTX + i] == v);
            }
            float w = ((c0 > 1) || (c1 > 1)) ? 1.5f : 1.0f;
            float cv0 = c[(size_t)sid * VDIM + v];
            float cv1 = c[(size_t)(SDIM + sid) * VDIM + v];
            if (w > 1.f) corr += 0.5f * (softplus(cv0) + softplus(cv1));
            if (c0 > 0) corr -= w * cv0;
            if (c1 > 0) corr -= w * cv1;
        }
    }
    atomicAdd(acc + 1, corr);
}

// ---------------- NLL over final logits (online softmax) ----------------
__global__ __launch_bounds__(256) void loss_kernel(
    const float* __restrict__ logits, const int* __restrict__ y, float* __restrict__ acc)
{
    int row = blockIdx.x;  // 0..1023
    int t = threadIdx.x;
    const float* lp = logits + (size_t)row * VDIM;
    float m = -3.4e38f, sum = 0.f;
    for (int i = t; i < VDIM; i += 256) {
        float x = lp[i];
        float nm = fmaxf(m, x);
        sum = sum * expf(m - nm) + expf(x - nm);
        m = nm;
    }
#pragma unroll
    for (int off = 32; off; off >>= 1) {
        float om = __shfl_down(m, off, 64);
        float os = __shfl_down(sum, off, 64);
        float nm = fmaxf(m, om);
        sum = sum * expf(m - nm) + os * expf(om - nm);
        m = nm;
    }
    __shared__ float sm[4], ss[4];
    int lane = t & 63, wave = t >> 6;
    if (lane == 0) { sm[wave] = m; ss[wave] = sum; }
    __syncthreads();
    if (t == 0) {
        float M = sm[0], S = ss[0];
        for (int wv = 1; wv < 4; ++wv) {
            float nm = fmaxf(M, sm[wv]);
            S = S * expf(M - nm) + ss[wv] * expf(sm[wv] - nm);
            M = nm;
        }
        int b = row >> 9, s = row & 511;
        int tgt = y[b * YSTR + s];
        float xt = lp[tgt];
        atomicAdd(acc, -(xt - M - logf(S)));
    }
}

__global__ void finalize_kernel(const float* __restrict__ acc, float* __restrict__ out)
{
    out[(size_t)NROWS * VDIM]     = acc[0] * (1.f / (float)NROWS);
    out[(size_t)NROWS * VDIM + 1] = acc[1] * (1.f / ((float)NROWS * (float)VDIM));
}

extern "C" void kernel_launch(void* const* d_in, const int* in_sizes, int n_in,
                              void* d_out, int out_size, void* d_ws, size_t ws_size,
                              hipStream_t stream)
{
    const float* emb  = (const float*)d_in[0];
    const float* Wlm  = (const float*)d_in[1];
    const float* Wctx = (const float*)d_in[2];
    const float* lnw  = (const float*)d_in[3];
    const int*   y    = (const int*)d_in[4];
    float* out = (float*)d_out;

    // ws layout (all 16B aligned)
    char* ws = (char*)d_ws;
    const size_t A_BYTES = (size_t)NROWS * DDIM * 2;       // 2 MB each
    const size_t W_BYTES = (size_t)VDIM * DDIM * 2;        // 65.536 MB each
    const size_t C_BYTES = (size_t)NROWS * VDIM * 4;       // 131.072 MB
    u16*   Alm   = (u16*)ws;
    u16*   Actx  = (u16*)(ws + A_BYTES);
    u16*   WlmB  = (u16*)(ws + 2 * A_BYTES);
    u16*   WctxB = (u16*)(ws + 2 * A_BYTES + W_BYTES);
    float* c     = (float*)(ws + 2 * A_BYTES + 2 * W_BYTES);
    float* acc   = (float*)(ws + 2 * A_BYTES + 2 * W_BYTES + C_BYTES);

    hipMemsetAsync(acc, 0, 2 * sizeof(float), stream);
    prep_a_kernel<<<NROWS, 256, 0, stream>>>(emb, lnw, Alm, Actx);
    cast_kernel<<<(VDIM * DDIM / 4) / 256, 256, 0, stream>>>((const float4*)Wlm,  (ushort4*)WlmB);
    cast_kernel<<<(VDIM * DDIM / 4) / 256, 256, 0, stream>>>((const float4*)Wctx, (ushort4*)WctxB);
    // 1000 wgs: (1024/256) * (32000/256) * 2, XCD-swizzled inside the kernel
    gemm_kernel<<<1000, 512, 0, stream>>>(Alm, WlmB, out, Actx, WctxB, c);
    conv_kernel<<<dim3(VDIM / 256, SDIM / CONV_CHUNK, BDIM), 256, 0, stream>>>(c, out, acc);
    corr_kernel<<<2, 256, 0, stream>>>(c, y, acc);
    loss_kernel<<<NROWS, 256, 0, stream>>>(out, y, acc);
    finalize_kernel<<<1, 1, 0, stream>>>(acc, out);
}

// Round 3
// 680.244 us; speedup vs baseline: 1.7022x; 1.0115x over previous
//
#include <hip/hip_runtime.h>
#include <hip/hip_bf16.h>

typedef unsigned short u16;
typedef unsigned int u32;
typedef __bf16 bf16x8 __attribute__((ext_vector_type(8)));
typedef float f32x4 __attribute__((ext_vector_type(4)));

#define SDIM 512
#define BDIM 2
#define DDIM 1024
#define VDIM 32000
#define FCTX 16
#define NROWS (BDIM * SDIM)          // 1024 GEMM M
#define YSTR (SDIM + FCTX - 1)       // 527
#define KCAT 2048                    // concat K: [Alm|Aconv] / [Wlm|Wctx]

__device__ __forceinline__ u16 f2bf(float f) {
    u32 u = __float_as_uint(f);
    u += 0x7fffu + ((u >> 16) & 1u);   // RNE
    return (u16)(u >> 16);
}

__device__ __forceinline__ float bf2f(u16 u) {
    return __uint_as_float((u32)u << 16);
}

__device__ __forceinline__ float softplus(float x) {
    return fmaxf(x, 0.f) + log1pf(expf(-fabsf(x)));
}

__device__ __forceinline__ void gload_lds16(const void* g, void* l) {
    __builtin_amdgcn_global_load_lds((const __attribute__((address_space(1))) void*)g,
                                     (__attribute__((address_space(3))) void*)l, 16, 0, 0);
}

// ---------------- prep: layernorm + bf16 cast; Alm lands in Acat[:, 0:1024] ----------------
__global__ __launch_bounds__(256) void prep_a_kernel(
    const float* __restrict__ emb, const float* __restrict__ lnw,
    u16* __restrict__ Acat, u16* __restrict__ ActxB)
{
    int row = blockIdx.x;
    int t = threadIdx.x;
    const float4* x4 = (const float4*)(emb + (size_t)row * DDIM);
    float4 v = x4[t];
    float s1 = v.x + v.y + v.z + v.w;
    float s2 = v.x*v.x + v.y*v.y + v.z*v.z + v.w*v.w;
#pragma unroll
    for (int off = 32; off; off >>= 1) {
        s1 += __shfl_down(s1, off, 64);
        s2 += __shfl_down(s2, off, 64);
    }
    __shared__ float r1[4], r2[4];
    int lane = t & 63, wave = t >> 6;
    if (lane == 0) { r1[wave] = s1; r2[wave] = s2; }
    __syncthreads();
    s1 = r1[0] + r1[1] + r1[2] + r1[3];
    s2 = r2[0] + r2[1] + r2[2] + r2[3];
    float mean = s1 * (1.f / DDIM);
    float var = s2 * (1.f / DDIM) - mean * mean;
    float rstd = rsqrtf(var + 1e-5f);
    float4 w = ((const float4*)lnw)[t];
    ushort4 a, b;
    a.x = f2bf(v.x); a.y = f2bf(v.y); a.z = f2bf(v.z); a.w = f2bf(v.w);
    b.x = f2bf((v.x - mean) * rstd * w.x);
    b.y = f2bf((v.y - mean) * rstd * w.y);
    b.z = f2bf((v.z - mean) * rstd * w.z);
    b.w = f2bf((v.w - mean) * rstd * w.w);
    ((ushort4*)(Acat + (size_t)row * KCAT))[t] = a;     // Alm half, row stride 2048
    ((ushort4*)(ActxB + (size_t)row * DDIM))[t] = b;
}

// ---------------- exp-decay conv folded into A-space: Aconv = ED * Actx ----------------
// context(b,s,:) = sum_i coef[i] * Actx(b, s-i, :)  ->  Acat[:, 1024:2048]
__global__ __launch_bounds__(256) void prep_conv_kernel(
    const u16* __restrict__ ActxB, u16* __restrict__ Acat)
{
    int row = blockIdx.x;            // b*SDIM + s
    int s = row & (SDIM - 1);
    int t = threadIdx.x;             // 4 dims each
    float coef[FCTX];
    float Z = 0.f;
#pragma unroll
    for (int i = 0; i < FCTX; ++i) { coef[i] = expf(-0.5f * i); Z += coef[i]; }
    float invZ = 1.f / Z;
    float4 sum = {0.f, 0.f, 0.f, 0.f};
#pragma unroll
    for (int i = 0; i < FCTX; ++i) {
        if (s - i >= 0) {            // zero-pad within batch
            ushort4 q = *(const ushort4*)(ActxB + (size_t)(row - i) * DDIM + t * 4);
            float k = coef[i] * invZ;
            sum.x += k * bf2f(q.x);
            sum.y += k * bf2f(q.y);
            sum.z += k * bf2f(q.z);
            sum.w += k * bf2f(q.w);
        }
    }
    ushort4 o;
    o.x = f2bf(sum.x); o.y = f2bf(sum.y); o.z = f2bf(sum.z); o.w = f2bf(sum.w);
    *(ushort4*)(Acat + (size_t)row * KCAT + DDIM + t * 4) = o;
}

// ---------------- cast W fp32 -> bf16 into interleaved Wcat[v][2048] ----------------
__global__ __launch_bounds__(256) void cast_kernel(
    const float4* __restrict__ src, u16* __restrict__ dstBase, int colOff)
{
    int i = blockIdx.x * 256 + threadIdx.x;   // over V*D/4
    int v = i >> 8;                            // D/4 = 256 float4 per row
    int d4 = i & 255;
    float4 f = src[i];
    ushort4 o;
    o.x = f2bf(f.x); o.y = f2bf(f.y); o.z = f2bf(f.z); o.w = f2bf(f.w);
    *(ushort4*)(dstBase + (size_t)v * KCAT + colOff + d4 * 4) = o;
}

// ---------------- GEMM core: 256x256 tile, BK=64, 8 waves, 8-phase counted-vmcnt ----------------
// Identical schedule/swizzle to the HW-verified round-2 kernel; K/LDA/LDB/SP templated.
// SP=true: no C write; softplus(acc) block-reduced into accbuf[1] (context-loss sum).

__device__ __forceinline__ void stage_half(const u16* __restrict__ mat, int lda,
                                           int grow0, int gcol0, char* lds_half, int t)
{
    int r0 = t >> 3;
    int swz = ((t & 7) ^ (r0 & 7)) * 8;     // inverse (= same) XOR on source col, elems
    const u16* g0 = mat + (size_t)(grow0 + r0) * lda + gcol0 + swz;
    gload_lds16(g0, lds_half + t * 16);
    gload_lds16(g0 + (size_t)64 * lda, lds_half + 8192 + t * 16);
}

#define MFMA16(a, b, c) __builtin_amdgcn_mfma_f32_16x16x32_bf16(a, b, c, 0, 0, 0)
#define VM4 asm volatile("s_waitcnt vmcnt(4)" ::: "memory")
#define VM0 asm volatile("s_waitcnt vmcnt(0)" ::: "memory")
#define NOP ((void)0)

#define PHASE(BB, Q, STG, VM) do {                                              \
    bf16x8 a00, a01, a10, a11;                                                  \
    if ((Q) == 0) {                                                             \
        _Pragma("unroll")                                                       \
        for (int j = 0; j < 4; ++j) {                                           \
            bfr[2*j]   = *(const bf16x8*)(Bln + (BB)*65536 + j*2048 + axor0);   \
            bfr[2*j+1] = *(const bf16x8*)(Bln + (BB)*65536 + j*2048 + axor1);   \
        }                                                                       \
    }                                                                           \
    { const char* Ab = Aln + (BB)*65536 + (2*(Q))*2048;                         \
      a00 = *(const bf16x8*)(Ab + axor0);                                       \
      a01 = *(const bf16x8*)(Ab + axor1);                                       \
      a10 = *(const bf16x8*)(Ab + 2048 + axor0);                                \
      a11 = *(const bf16x8*)(Ab + 2048 + axor1); }                              \
    STG; VM;                                                                    \
    __builtin_amdgcn_s_barrier();                                               \
    asm volatile("s_waitcnt lgkmcnt(0)" ::: "memory");                          \
    __builtin_amdgcn_sched_barrier(0);                                          \
    __builtin_amdgcn_s_setprio(1);                                              \
    _Pragma("unroll")                                                           \
    for (int j = 0; j < 4; ++j) {                                               \
        acc[2*(Q)][j]   = MFMA16(a00, bfr[2*j],   acc[2*(Q)][j]);               \
        acc[2*(Q)][j]   = MFMA16(a01, bfr[2*j+1], acc[2*(Q)][j]);               \
        acc[2*(Q)+1][j] = MFMA16(a10, bfr[2*j],   acc[2*(Q)+1][j]);             \
        acc[2*(Q)+1][j] = MFMA16(a11, bfr[2*j+1], acc[2*(Q)+1][j]);             \
    }                                                                           \
    __builtin_amdgcn_s_setprio(0);                                              \
    __builtin_amdgcn_s_barrier();                                               \
} while (0)

#define STAGE_A(BB, H, KT) stage_half(Amat, LDA, bm256 + (H)*128, (KT)*64, ldsb + (BB)*65536 + (H)*16384, t)
#define STAGE_B(BB, H, KT) stage_half(Bmat, LDB, bn256 + (H)*128, (KT)*64, ldsb + (BB)*65536 + 32768 + (H)*16384, t)

template<int KD, int LDA, int LDB, bool SP>
__device__ __forceinline__ void gemm_core(
    const u16* __restrict__ Amat, const u16* __restrict__ Bmat,
    float* __restrict__ C, float* __restrict__ accbuf,
    char* ldsb, int bm, int bn, int t)
{
    constexpr int N = VDIM;
    constexpr int NKT = KD / 64;
    int lane = t & 63, wave = t >> 6;
    int wr = wave >> 2, wc = wave & 3;       // 2 x 4 wave grid; per-wave out = 128x64
    int l15 = lane & 15, lg = lane >> 4, l7 = lane & 7;
    int bm256 = bm * 256, bn256 = bn * 256;

    int axor0 = (lg * 16) ^ (l7 << 4);
    int axor1 = (64 + lg * 16) ^ (l7 << 4);
    const char* Aln = ldsb + wr * 16384 + l15 * 128;
    const char* Bln = ldsb + 32768 + (wc >> 1) * 16384 + ((wc & 1) * 64 + l15) * 128;

    f32x4 acc[8][4] = {};
    bf16x8 bfr[8];

    // prologue: buf0 <- K0 (all 4 halves), buf1 <- K1 (B halves only)
    STAGE_A(0, 0, 0); STAGE_A(0, 1, 0); STAGE_B(0, 0, 0); STAGE_B(0, 1, 0);
    STAGE_B(1, 0, 1); STAGE_B(1, 1, 1);
    VM4;
    __builtin_amdgcn_s_barrier();

    for (int m = 0; m < NKT / 2 - 1; ++m) {
        int k1 = 2 * m + 1, k2 = 2 * m + 2, k3 = 2 * m + 3;
        PHASE(0, 0, STAGE_A(1, 0, k1), NOP);
        PHASE(0, 1, STAGE_A(1, 1, k1), NOP);
        PHASE(0, 2, STAGE_B(0, 0, k2), NOP);
        PHASE(0, 3, STAGE_B(0, 1, k2), VM4);
        PHASE(1, 0, STAGE_A(0, 0, k2), NOP);
        PHASE(1, 1, STAGE_A(0, 1, k2), NOP);
        PHASE(1, 2, STAGE_B(1, 0, k3), NOP);
        PHASE(1, 3, STAGE_B(1, 1, k3), VM4);
    }
    // peeled last iter: only K(NKT-1)'s A halves remain to stage; drain before buf1 reads.
    PHASE(0, 0, STAGE_A(1, 0, NKT - 1), NOP);
    PHASE(0, 1, STAGE_A(1, 1, NKT - 1), NOP);
    PHASE(0, 2, NOP, NOP);
    PHASE(0, 3, NOP, VM0);
    PHASE(1, 0, NOP, NOP);
    PHASE(1, 1, NOP, NOP);
    PHASE(1, 2, NOP, NOP);
    PHASE(1, 3, NOP, NOP);

    if constexpr (!SP) {
        // epilogue: C/D map col = lane&15, row = (lane>>4)*4 + reg
        int row0 = bm256 + wr * 128 + lg * 4;
        int col0 = bn256 + wc * 64 + l15;
#pragma unroll
        for (int i = 0; i < 8; ++i)
#pragma unroll
            for (int j = 0; j < 4; ++j) {
                float* cp = C + (size_t)(row0 + i * 16) * N + col0 + j * 16;
#pragma unroll
                for (int r = 0; r < 4; ++r) cp[(size_t)r * N] = acc[i][j][r];
            }
    } else {
        // softplus-sum of c values straight from registers; c is never written.
        float sp = 0.f;
#pragma unroll
        for (int i = 0; i < 8; ++i)
#pragma unroll
            for (int j = 0; j < 4; ++j)
#pragma unroll
                for (int r = 0; r < 4; ++r)
                    sp += softplus(acc[i][j][r]);
#pragma unroll
        for (int off = 32; off; off >>= 1) sp += __shfl_down(sp, off, 64);
        __syncthreads();
        float* red = (float*)ldsb;
        if (lane == 0) red[wave] = sp;
        __syncthreads();
        if (t == 0) {
            float s = 0.f;
            for (int w2 = 0; w2 < 8; ++w2) s += red[w2];
            atomicAdd(accbuf + 1, s);
        }
    }
}

// z=0 (500 wgs): out = Acat @ Wcat^T, K=2048  (logits = lm + context, fused)
// z=1 (500 wgs): softplus-sum of Actx @ Wctx^T, K=1024 (no C write)
__global__ __launch_bounds__(512, 2) void gemm_kernel(
    const u16* __restrict__ Acat, const u16* __restrict__ Wcat, float* __restrict__ out,
    const u16* __restrict__ ActxB, float* __restrict__ accbuf)
{
    __shared__ __align__(16) char lds_s[131072];
    // XCD-aware swizzle: 1000 % 8 == 0, simple form is bijective; 4 bm-tiles sharing a
    // W-panel are consecutive in wg -> co-resident on one XCD L2.
    int bid = blockIdx.x;
    int wg = (bid & 7) * 125 + (bid >> 3);
    int z = (wg >= 500) ? 1 : 0;
    int rem = wg - z * 500;
    int bn = rem >> 2, bm = rem & 3;
    if (z == 0)
        gemm_core<KCAT, KCAT, KCAT, false>(Acat, Wcat, out, nullptr, lds_s, bm, bn, threadIdx.x);
    else
        gemm_core<DDIM, DDIM, KCAT, true>(ActxB, Wcat + DDIM, nullptr, accbuf, lds_s, bm, bn, threadIdx.x);
}

// ---------------- BCE correction terms: c recomputed on the fly (c matrix is virtual) ----------------
// One (sid, k) task per thread; 64 blocks x 256 threads = 512 x 32 tasks.
// All loops compile-time unrolled -> tok[] stays in VGPRs (no scratch).
__global__ __launch_bounds__(256) void corr_kernel(
    const u16* __restrict__ ActxB, const u16* __restrict__ Wcat,
    const int* __restrict__ y, float* __restrict__ acc)
{
    int gid = blockIdx.x * 256 + threadIdx.x;   // 0..16383
    int sid = gid >> 5, k = gid & 31;
    int tok[2 * FCTX];
#pragma unroll
    for (int i = 0; i < FCTX; ++i) {
        tok[i] = y[sid + i];
        tok[FCTX + i] = y[YSTR + sid + i];
    }
    float corr = 0.f;
    int v = tok[k];
    bool seen = false;
#pragma unroll
    for (int j = 0; j < 2 * FCTX; ++j) seen |= ((j < k) && (tok[j] == v));
    if (!seen) {
        int c0 = 0, c1 = 0;
#pragma unroll
        for (int i = 0; i < FCTX; ++i) {
            c0 += (tok[i] == v);
            c1 += (tok[FCTX + i] == v);
        }
        float w = ((c0 > 1) || (c1 > 1)) ? 1.5f : 1.0f;
        const u16* a0 = ActxB + (size_t)sid * DDIM;
        const u16* a1 = ActxB + (size_t)(SDIM + sid) * DDIM;
        const u16* wv = Wcat + (size_t)v * KCAT + DDIM;   // Wctx half
        float cv0 = 0.f, cv1 = 0.f;
        for (int d = 0; d < DDIM; d += 4) {
            ushort4 wq = *(const ushort4*)(wv + d);
            ushort4 q0 = *(const ushort4*)(a0 + d);
            ushort4 q1 = *(const ushort4*)(a1 + d);
            float w0 = bf2f(wq.x), w1 = bf2f(wq.y), w2 = bf2f(wq.z), w3 = bf2f(wq.w);
            cv0 += bf2f(q0.x) * w0 + bf2f(q0.y) * w1 + bf2f(q0.z) * w2 + bf2f(q0.w) * w3;
            cv1 += bf2f(q1.x) * w0 + bf2f(q1.y) * w1 + bf2f(q1.z) * w2 + bf2f(q1.w) * w3;
        }
        if (w > 1.f) corr += 0.5f * (softplus(cv0) + softplus(cv1));
        if (c0 > 0) corr -= w * cv0;
        if (c1 > 0) corr -= w * cv1;
    }
    // block reduce -> one atomic per block
#pragma unroll
    for (int off = 32; off; off >>= 1) corr += __shfl_down(corr, off, 64);
    __shared__ float rs[4];
    int lane = threadIdx.x & 63, wave = threadIdx.x >> 6;
    if (lane == 0) rs[wave] = corr;
    __syncthreads();
    if (threadIdx.x == 0) atomicAdd(acc + 1, rs[0] + rs[1] + rs[2] + rs[3]);
}

// ---------------- NLL over final logits (online softmax) ----------------
__global__ __launch_bounds__(256) void loss_kernel(
    const float* __restrict__ logits, const int* __restrict__ y, float* __restrict__ acc)
{
    int row = blockIdx.x;  // 0..1023
    int t = threadIdx.x;
    const float* lp = logits + (size_t)row * VDIM;
    float m = -3.4e38f, sum = 0.f;
    for (int i = t; i < VDIM; i += 256) {
        float x = lp[i];
        float nm = fmaxf(m, x);
        sum = sum * expf(m - nm) + expf(x - nm);
        m = nm;
    }
#pragma unroll
    for (int off = 32; off; off >>= 1) {
        float om = __shfl_down(m, off, 64);
        float os = __shfl_down(sum, off, 64);
        float nm = fmaxf(m, om);
        sum = sum * expf(m - nm) + os * expf(om - nm);
        m = nm;
    }
    __shared__ float sm[4], ss[4];
    int lane = t & 63, wave = t >> 6;
    if (lane == 0) { sm[wave] = m; ss[wave] = sum; }
    __syncthreads();
    if (t == 0) {
        float M = sm[0], S = ss[0];
        for (int wv = 1; wv < 4; ++wv) {
            float nm = fmaxf(M, sm[wv]);
            S = S * expf(M - nm) + ss[wv] * expf(sm[wv] - nm);
            M = nm;
        }
        int b = row >> 9, s = row & 511;
        int tgt = y[b * YSTR + s];
        float xt = lp[tgt];
        atomicAdd(acc, -(xt - M - logf(S)));
    }
}

__global__ void finalize_kernel(const float* __restrict__ acc, float* __restrict__ out)
{
    out[(size_t)NROWS * VDIM]     = acc[0] * (1.f / (float)NROWS);
    out[(size_t)NROWS * VDIM + 1] = acc[1] * (1.f / ((float)NROWS * (float)VDIM));
}

extern "C" void kernel_launch(void* const* d_in, const int* in_sizes, int n_in,
                              void* d_out, int out_size, void* d_ws, size_t ws_size,
                              hipStream_t stream)
{
    const float* emb  = (const float*)d_in[0];
    const float* Wlm  = (const float*)d_in[1];
    const float* Wctx = (const float*)d_in[2];
    const float* lnw  = (const float*)d_in[3];
    const int*   y    = (const int*)d_in[4];
    float* out = (float*)d_out;

    // ws layout (all 16B aligned): total ~137 MB (was 266 MB; c matrix is now virtual)
    char* ws = (char*)d_ws;
    const size_t ACAT_BYTES = (size_t)NROWS * KCAT * 2;    // 4 MB   [Alm | Aconv]
    const size_t ACTX_BYTES = (size_t)NROWS * DDIM * 2;    // 2 MB
    const size_t WCAT_BYTES = (size_t)VDIM * KCAT * 2;     // 131.072 MB [Wlm | Wctx]
    u16*   Acat  = (u16*)ws;
    u16*   ActxB = (u16*)(ws + ACAT_BYTES);
    u16*   Wcat  = (u16*)(ws + ACAT_BYTES + ACTX_BYTES);
    float* acc   = (float*)(ws + ACAT_BYTES + ACTX_BYTES + WCAT_BYTES);

    hipMemsetAsync(acc, 0, 2 * sizeof(float), stream);
    prep_a_kernel<<<NROWS, 256, 0, stream>>>(emb, lnw, Acat, ActxB);
    prep_conv_kernel<<<NROWS, 256, 0, stream>>>(ActxB, Acat);
    cast_kernel<<<(VDIM * DDIM / 4) / 256, 256, 0, stream>>>((const float4*)Wlm,  Wcat, 0);
    cast_kernel<<<(VDIM * DDIM / 4) / 256, 256, 0, stream>>>((const float4*)Wctx, Wcat, DDIM);
    // 1000 wgs: 500 logits-GEMM (K=2048) + 500 softplus-GEMM (K=1024)
    gemm_kernel<<<1000, 512, 0, stream>>>(Acat, Wcat, out, ActxB, acc);
    corr_kernel<<<64, 256, 0, stream>>>(ActxB, Wcat, y, acc);
    loss_kernel<<<NROWS, 256, 0, stream>>>(out, y, acc);
    finalize_kernel<<<1, 1, 0, stream>>>(acc, out);
}